// Round 7
// baseline (14.187 us; speedup 1.0000x reference)
//
#include <hip/hip_runtime.h>

// Problem constants (B,C,H,W,L) = (4,16,256,256,25)
#define HWPIX 65536   // H*W
#define NCH   16
#define NLBL  25

// R1-R6 model history:
//  - divergent LDS gathers cost ~21-34 cyc/instr (address-divergence limited)
//  - BUT halving gather count (R6) only moved 14.7->13.9 us => gathers are
//    no longer the binder.  Suspect: compiler hoists the fully-unrolled
//    weight gathers -> 160-256 VGPRs -> 2 waves/SIMD -> latency-bound.
// Fix: __launch_bounds__(256,4) caps VGPR at 128 (4 waves/SIMD) and the
// o-loop is chunked (4 outputs, 8 live uint4 = 32 VGPR of weights).
// Weights bf16-packed, 8 per uint4: w8[k][l] = weight[l][flat 8k..8k+7],
// flat = o*16+c -> k = o*2 + (c/8).  32 ds_read_b128 per pixel.
// bf16 absmax err measured 0.031 << 0.143 threshold.

__device__ __forceinline__ unsigned int pack_bf16_rtn(float lo, float hi) {
    unsigned int ul = __float_as_uint(lo);
    unsigned int uh = __float_as_uint(hi);
    ul += 0x7FFFu + ((ul >> 16) & 1u);   // round-to-nearest-even
    uh += 0x7FFFu + ((uh >> 16) & 1u);
    return (ul >> 16) | (uh & 0xFFFF0000u);
}

__global__ __launch_bounds__(256, 4) void invconv_kernel(
    const float* __restrict__ x,
    const int*   __restrict__ labels,
    const float* __restrict__ weight,
    const float* __restrict__ bias,
    float*       __restrict__ out)
{
    __shared__ uint4 w8[32][32];   // 16 KiB

    const int tid = threadIdx.x;

    // One pixel per thread: 1024 blocks x 256 thr = 16 waves/CU (4/SIMD).
    const int t = blockIdx.x * 256 + tid;
    const int b = t >> 16;               // / HWPIX
    const int p = t & 65535;             // % HWPIX

    // Issue label + x loads BEFORE staging so HBM latency overlaps it.
    const int l0 = labels[b * HWPIX + p];

    float xv[NCH];
    const float* xb = x + b * (NCH * HWPIX) + p;
    #pragma unroll
    for (int c = 0; c < NCH; ++c)
        xv[c] = xb[c * HWPIX];           // 4B/lane, coalesced

    // Stage + pack weights: 25*32 = 800 uint4 slots, f = l*32 + k.
    #pragma unroll
    for (int i = 0; i < 4; ++i) {
        int f = tid + i * 256;           // < 1024
        if (f < NLBL * 32) {
            int l = f >> 5;
            int k = f & 31;
            const float* wp = weight + l * 256 + k * 8;
            const float4 a = *reinterpret_cast<const float4*>(wp);
            const float4 c = *reinterpret_cast<const float4*>(wp + 4);
            uint4 pk;
            pk.x = pack_bf16_rtn(a.x, a.y);
            pk.y = pack_bf16_rtn(a.z, a.w);
            pk.z = pack_bf16_rtn(c.x, c.y);
            pk.w = pack_bf16_rtn(c.z, c.w);
            w8[k][l] = pk;
        }
    }
    __syncthreads();

    const float bias0 = bias[l0];
    float* ob = out + b * (NCH * HWPIX) + p;

    // 4 chunks of 4 outputs: live set = 8 uint4 (32 VGPR) + xv (16) + misc.
    #pragma unroll
    for (int og = 0; og < 4; ++og) {
        uint4 w[8];
        #pragma unroll
        for (int j = 0; j < 8; ++j)
            w[j] = w8[og * 8 + j][l0];   // k = og*8+j  (o = og*4+j/2, q = j&1)

        #pragma unroll
        for (int j2 = 0; j2 < 4; ++j2) { // output o = og*4 + j2
            const uint4 wa = w[j2 * 2 + 0];   // channels 0..7
            const uint4 wb = w[j2 * 2 + 1];   // channels 8..15
            float acc = bias0;
            acc = fmaf(__uint_as_float(wa.x << 16),          xv[0],  acc);
            acc = fmaf(__uint_as_float(wa.x & 0xFFFF0000u),  xv[1],  acc);
            acc = fmaf(__uint_as_float(wa.y << 16),          xv[2],  acc);
            acc = fmaf(__uint_as_float(wa.y & 0xFFFF0000u),  xv[3],  acc);
            acc = fmaf(__uint_as_float(wa.z << 16),          xv[4],  acc);
            acc = fmaf(__uint_as_float(wa.z & 0xFFFF0000u),  xv[5],  acc);
            acc = fmaf(__uint_as_float(wa.w << 16),          xv[6],  acc);
            acc = fmaf(__uint_as_float(wa.w & 0xFFFF0000u),  xv[7],  acc);
            acc = fmaf(__uint_as_float(wb.x << 16),          xv[8],  acc);
            acc = fmaf(__uint_as_float(wb.x & 0xFFFF0000u),  xv[9],  acc);
            acc = fmaf(__uint_as_float(wb.y << 16),          xv[10], acc);
            acc = fmaf(__uint_as_float(wb.y & 0xFFFF0000u),  xv[11], acc);
            acc = fmaf(__uint_as_float(wb.z << 16),          xv[12], acc);
            acc = fmaf(__uint_as_float(wb.z & 0xFFFF0000u),  xv[13], acc);
            acc = fmaf(__uint_as_float(wb.w << 16),          xv[14], acc);
            acc = fmaf(__uint_as_float(wb.w & 0xFFFF0000u),  xv[15], acc);
            ob[(og * 4 + j2) * HWPIX] = acc;
        }
    }
}

extern "C" void kernel_launch(void* const* d_in, const int* in_sizes, int n_in,
                              void* d_out, int out_size, void* d_ws, size_t ws_size,
                              hipStream_t stream) {
    const float* x      = (const float*)d_in[0];
    const int*   labels = (const int*)  d_in[1];
    const float* weight = (const float*)d_in[2];
    const float* bias   = (const float*)d_in[3];
    float*       out    = (float*)d_out;

    // total pixels = 262144; 1 px/thread, 256 threads/block -> 1024 blocks
    dim3 grid(1024), block(256);
    invconv_kernel<<<grid, block, 0, stream>>>(x, labels, weight, bias, out);
}